// Round 6
// baseline (78.572 us; speedup 1.0000x reference)
//
#include <hip/hip_runtime.h>

#define BATCH 256
#define CH    512
#define HW    196      // 14*14
#define HID   128      // C / RED
#define HW4   49       // float4s per (b,c) row
#define ROW4  (CH * HW4)   // 25088 float4s per batch
#define NTHR  1024

typedef float f32x4 __attribute__((ext_vector_type(4)));

static __device__ __forceinline__ float dot4(const f32x4 a, const f32x4 b) {
    return a.x * b.x + a.y * b.y + a.z * b.z + a.w * b.w;
}

// ---------------------------------------------------------------------------
// K1: one block per batch. Pool (high-ILP: 2 channels x 3 float4 loads all
// issued before FMAs) -> MLP -> stable rank -> mask.  __syncthreads only.
// ---------------------------------------------------------------------------
__global__ __launch_bounds__(NTHR) void pool_mlp_kernel(
        const f32x4* __restrict__ x4,
        const f32x4* __restrict__ w4,    // dct weight, [CH][49] f4
        const float* __restrict__ w1,    // [HID][CH]
        const float* __restrict__ w2,    // [CH][HID]
        const int*   __restrict__ kt,    // [BATCH]
        float* __restrict__ bounded,
        float* __restrict__ raw_out,
        float* __restrict__ mask_out,
        float* __restrict__ s_out) {
    __shared__ float s_lds[CH];
    __shared__ float h_lds[HID];
    __shared__ float r_lds[CH];

    const int b   = blockIdx.x;
    const int tid = threadIdx.x;
    const f32x4* xb = x4 + (size_t)b * ROW4;
    const int k = kt[b];

    // ---- phase 1: DCT pooling. 64 groups of 16 lanes; channels c and c+256
    // per iteration, 12 independent float4 loads in flight before any FMA ----
    {
        const int g  = tid >> 4;          // 0..63
        const int gl = tid & 15;
        #pragma unroll
        for (int it = 0; it < 4; ++it) {
            const int cA = g + it * 64;
            const int cB = cA + 256;
            const f32x4* xpA = xb + (size_t)cA * HW4;
            const f32x4* wpA = w4 + (size_t)cA * HW4;
            const f32x4* xpB = xb + (size_t)cB * HW4;
            const f32x4* wpB = w4 + (size_t)cB * HW4;
            // issue all loads first (independent -> single vmcnt batch)
            const f32x4 a0 = xpA[gl];      const f32x4 a1 = xpA[gl + 16];
            const f32x4 a2 = xpA[gl + 32];
            const f32x4 b0 = xpB[gl];      const f32x4 b1 = xpB[gl + 16];
            const f32x4 b2 = xpB[gl + 32];
            const f32x4 u0 = wpA[gl];      const f32x4 u1 = wpA[gl + 16];
            const f32x4 u2 = wpA[gl + 32];
            const f32x4 v0 = wpB[gl];      const f32x4 v1 = wpB[gl + 16];
            const f32x4 v2 = wpB[gl + 32];
            float vA = dot4(a0, u0) + dot4(a1, u1) + dot4(a2, u2);
            float vB = dot4(b0, v0) + dot4(b1, v1) + dot4(b2, v2);
            if (gl == 0) {
                vA += dot4(xpA[48], wpA[48]);
                vB += dot4(xpB[48], wpB[48]);
            }
            vA += __shfl_xor(vA, 8, 64);
            vA += __shfl_xor(vA, 4, 64);
            vA += __shfl_xor(vA, 2, 64);
            vA += __shfl_xor(vA, 1, 64);
            vB += __shfl_xor(vB, 8, 64);
            vB += __shfl_xor(vB, 4, 64);
            vB += __shfl_xor(vB, 2, 64);
            vB += __shfl_xor(vB, 1, 64);
            if (gl == 0) {
                s_lds[cA] = vA; s_out[b * CH + cA] = vA;
                s_lds[cB] = vB; s_out[b * CH + cB] = vB;
            }
        }
    }
    __syncthreads();

    // ---- phase 2a: hidden = relu(s @ w1.T); 8 threads per hidden unit ----
    {
        const int u  = tid >> 3;          // 0..127
        const int j0 = tid & 7;
        float h = 0.0f;
        const float* w1p = w1 + (size_t)u * CH;
        for (int j = j0; j < CH; j += 8) h += s_lds[j] * w1p[j];
        h += __shfl_xor(h, 4, 64);
        h += __shfl_xor(h, 2, 64);
        h += __shfl_xor(h, 1, 64);
        if (j0 == 0) h_lds[u] = fmaxf(h, 0.0f);
    }
    __syncthreads();

    // ---- phase 2b: raw[c] = h . w2[c]; 2 threads per channel.
    // Summation structure identical for every c -> exact ties preserved. ----
    {
        const int c    = tid >> 1;        // 0..511
        const int half = tid & 1;
        float r = 0.0f;
        const float* w2p = w2 + (size_t)c * HID + half * 64;
        #pragma unroll 4
        for (int j = 0; j < 64; ++j) r += h_lds[half * 64 + j] * w2p[j];
        const float other = __shfl_xor(r, 1, 64);
        const float rt = (half == 0) ? (r + other) : (other + r);
        if (half == 0) {
            r_lds[c] = rt;
            raw_out[b * CH + c] = rt;
            bounded[b * CH + c] = tanhf(rt);
        }
    }
    __syncthreads();

    // ---- phase 2c: stable descending rank vs k -> mask ----
    {
        const int c    = tid >> 1;
        const int half = tid & 1;
        const float r = r_lds[c];
        int cnt = 0;
        #pragma unroll 8
        for (int j = half * 256; j < half * 256 + 256; ++j) {
            const float rj = r_lds[j];
            cnt += (rj > r) || (rj == r && j < c);
        }
        cnt += __shfl_xor(cnt, 1, 64);
        if (half == 0) mask_out[b * CH + c] = (cnt < k) ? 1.0f : 0.0f;
    }
}

// ---------------------------------------------------------------------------
// K2: gate. 8192 blocks x 256 (32 waves/CU). x is L3-hot from K1.
// mask is exactly 0/1: pass-through or zero-store (no x read when 0).
// ---------------------------------------------------------------------------
__global__ __launch_bounds__(256) void gate_kernel(const f32x4* __restrict__ x4,
                                                   const float* __restrict__ mask,
                                                   f32x4* __restrict__ out4) {
    const int total4 = BATCH * CH * HW4;             // 6,422,528
    const int stride = gridDim.x * blockDim.x;
    for (int i = blockIdx.x * blockDim.x + threadIdx.x; i < total4; i += stride) {
        const int row = i / HW4;                     // magic-mul division
        const float m = mask[row];
        f32x4 v;
        if (m != 0.0f) v = x4[i];
        else           v = (f32x4)(0.0f);
        __builtin_nontemporal_store(v, &out4[i]);
    }
}

extern "C" void kernel_launch(void* const* d_in, const int* in_sizes, int n_in,
                              void* d_out, int out_size, void* d_ws, size_t ws_size,
                              hipStream_t stream) {
    const f32x4* x4   = (const f32x4*)d_in[0];   // [256,512,14,14]
    const f32x4* w4   = (const f32x4*)d_in[1];   // [512,14,14]
    const float* w1   = (const float*)d_in[2];   // [128,512]
    const float* w2   = (const float*)d_in[3];   // [512,128]
    const int*   kt   = (const int*)d_in[4];     // [256]

    float* out     = (float*)d_out;                          // 256*512*196
    float* bounded = out + (size_t)BATCH * CH * HW;
    float* raw     = bounded + BATCH * CH;
    float* mask    = raw + BATCH * CH;
    float* s       = mask + BATCH * CH;

    pool_mlp_kernel<<<BATCH, NTHR, 0, stream>>>(
        x4, w4, w1, w2, kt, bounded, raw, mask, s);
    gate_kernel<<<8192, 256, 0, stream>>>(x4, mask, (f32x4*)out);
}

// Round 8
// 65.842 us; speedup vs baseline: 1.1933x; 1.1933x over previous
//
#include <hip/hip_runtime.h>

#define BATCH 256
#define CH    512
#define HW    196      // 14*14
#define HID   128      // C / RED
#define HW4   49       // float4s per (b,c) row
#define NROWS (BATCH * CH)
#define TOT4  (BATCH * CH * HW4)

typedef float f32x4 __attribute__((ext_vector_type(4)));

static __device__ __forceinline__ float dot4(const f32x4 a, const f32x4 b) {
    return a.x * b.x + a.y * b.y + a.z * b.z + a.w * b.w;
}

// ---------------------------------------------------------------------------
// K1: DCT pooling. 16-lane group per row, float4 loads. 8192 blocks x 256
// -> 8 blocks/CU: streaming MLP (proven round 3/7).
// ---------------------------------------------------------------------------
__global__ __launch_bounds__(256) void pool_kernel(const f32x4* __restrict__ x4,
                                                   const f32x4* __restrict__ w4,
                                                   float* __restrict__ s) {
    const int tid = threadIdx.x;
    const int gl  = tid & 15;
    const int row = blockIdx.x * 16 + (tid >> 4);
    const f32x4* xp = x4 + (size_t)row * HW4;
    const f32x4* wp = w4 + (size_t)(row & (CH - 1)) * HW4;

    const f32x4 a0 = xp[gl];      const f32x4 a1 = xp[gl + 16];
    const f32x4 a2 = xp[gl + 32];
    const f32x4 u0 = wp[gl];      const f32x4 u1 = wp[gl + 16];
    const f32x4 u2 = wp[gl + 32];
    float v = dot4(a0, u0) + dot4(a1, u1) + dot4(a2, u2);
    if (gl == 0) v += dot4(xp[48], wp[48]);

    v += __shfl_xor(v, 8, 64);
    v += __shfl_xor(v, 4, 64);
    v += __shfl_xor(v, 2, 64);
    v += __shfl_xor(v, 1, 64);
    if (gl == 0) s[row] = v;
}

// ---------------------------------------------------------------------------
// K2: MLP + tanh + stable rank mask. One 1024-thread block per batch.
// UNIFORMITY RULE: each channel's raw is produced by ONE static instruction
// sequence shared by all threads (2 threads/channel, canonical-order combine)
// -> bitwise-identical raw across channels -> rank == c -> mask matches ref.
// All LDS reads are b128 broadcasts (bit-exact, ~4x fewer DS ops than r6).
// ---------------------------------------------------------------------------
__global__ __launch_bounds__(1024) void mlp_kernel(const float* __restrict__ s,
                                                   const float* __restrict__ w1,
                                                   const float* __restrict__ w2,
                                                   const int*   __restrict__ kt,
                                                   float* __restrict__ bounded,
                                                   float* __restrict__ raw_out,
                                                   float* __restrict__ mask_out) {
    __shared__ float s_lds[CH];
    __shared__ float h_lds[HID];
    __shared__ float r_lds[CH];

    const int b   = blockIdx.x;
    const int tid = threadIdx.x;
    const int k   = kt[b];

    if (tid < CH / 4) ((f32x4*)s_lds)[tid] = ((const f32x4*)(s + b * CH))[tid];
    __syncthreads();

    // 2a: hidden[u] = relu(s . w1[u]); 8 threads/unit, b128 reads, stride 8
    {
        const int u  = tid >> 3;          // 0..127
        const int j0 = tid & 7;
        const f32x4* sv  = (const f32x4*)s_lds;
        const f32x4* w1v = (const f32x4*)(w1 + (size_t)u * CH);
        float h = 0.0f;
        #pragma unroll
        for (int t = 0; t < 16; ++t) h += dot4(sv[j0 + 8 * t], w1v[j0 + 8 * t]);
        h += __shfl_xor(h, 4, 64);        // fp add commutative: xor-butterfly ok
        h += __shfl_xor(h, 2, 64);
        h += __shfl_xor(h, 1, 64);
        if (j0 == 0) h_lds[u] = fmaxf(h, 0.0f);
    }
    __syncthreads();

    // 2b: raw[c] = h . w2[c]; 2 threads/channel (one half each, same code),
    // canonical combine order -> identical bits for every channel.
    const int c    = tid >> 1;            // 0..511
    const int half = tid & 1;
    float rt;
    {
        const f32x4* hv  = (const f32x4*)h_lds;
        const f32x4* w2v = (const f32x4*)(w2 + (size_t)c * HID);
        float r = 0.0f;
        #pragma unroll
        for (int t = 0; t < 16; ++t) r += dot4(hv[half * 16 + t], w2v[half * 16 + t]);
        const float other = __shfl_xor(r, 1, 64);
        rt = (half == 0) ? (r + other) : (other + r);   // canonical order
        if (half == 0) {
            r_lds[c] = rt;
            raw_out[b * CH + c] = rt;
            bounded[b * CH + c] = tanhf(rt);
        }
    }
    __syncthreads();

    // 2c: stable descending rank; b128 reads (bit-exact), 2 threads/channel
    {
        int cnt = 0;
        const f32x4* rv = (const f32x4*)r_lds;
        #pragma unroll 8
        for (int j4 = half * 64; j4 < half * 64 + 64; ++j4) {
            const f32x4 rj = rv[j4];
            #pragma unroll
            for (int m = 0; m < 4; ++m) {
                const float rjm = rj[m];
                const int j = j4 * 4 + m;
                cnt += (rjm > rt) || (rjm == rt && j < c);
            }
        }
        cnt += __shfl_xor(cnt, 1, 64);
        if (half == 0) mask_out[b * CH + c] = (cnt < k) ? 1.0f : 0.0f;
    }
}

// ---------------------------------------------------------------------------
// K3: gate. mask exactly 0/1: pass-through or zero-store (no x read for 0).
// Plain stores this round (NT-store A/B vs round 3's NT).
// ---------------------------------------------------------------------------
__global__ __launch_bounds__(256) void gate_kernel(const f32x4* __restrict__ x4,
                                                   const float* __restrict__ mask,
                                                   f32x4* __restrict__ out4) {
    const int stride = gridDim.x * blockDim.x;
    for (int i = blockIdx.x * blockDim.x + threadIdx.x; i < TOT4; i += stride) {
        const int row = i / HW4;                     // magic-mul division
        const float m = mask[row];
        f32x4 v;
        if (m != 0.0f) v = x4[i];
        else           v = (f32x4)(0.0f);
        out4[i] = v;
    }
}

extern "C" void kernel_launch(void* const* d_in, const int* in_sizes, int n_in,
                              void* d_out, int out_size, void* d_ws, size_t ws_size,
                              hipStream_t stream) {
    const f32x4* x4   = (const f32x4*)d_in[0];   // [256,512,14,14]
    const f32x4* w4   = (const f32x4*)d_in[1];   // [512,14,14]
    const float* w1   = (const float*)d_in[2];   // [128,512]
    const float* w2   = (const float*)d_in[3];   // [512,128]
    const int*   kt   = (const int*)d_in[4];     // [256]

    float* out     = (float*)d_out;                          // 256*512*196
    float* bounded = out + (size_t)BATCH * CH * HW;
    float* raw     = bounded + BATCH * CH;
    float* mask    = raw + BATCH * CH;
    float* s       = mask + BATCH * CH;

    pool_kernel<<<NROWS / 16, 256, 0, stream>>>(x4, w4, s);
    mlp_kernel<<<BATCH, 1024, 0, stream>>>(s, w1, w2, kt, bounded, raw, mask);
    gate_kernel<<<8192, 256, 0, stream>>>(x4, mask, (f32x4*)out);
}